// Round 2
// baseline (620.435 us; speedup 1.0000x reference)
//
#include <hip/hip_runtime.h>

// GumbelCodebook: y = one_hot(argmax(logits+gumbel)), z = codebook[argmax]
// (forward value of straight-through estimator: y_hard - y_soft + y_soft == y_hard
//  exactly in IEEE for non-argmax lanes, 1 +/- 1ulp at argmax -> well under threshold)
// Shapes: logits/gumbel [8,4096,2048] f32, codebook [2048,256] f32
// Outputs concatenated in d_out: z [8,4096,256] then y [8,4096,2048], f32.
//
// R2 structure: ONE WAVE PER TOKEN. No LDS, no barriers, 16 float4 loads in
// flight per lane, pure shfl_xor butterfly argmax. (R1's block-per-token had
// 2 barriers + serial tid==0 section -> latency-bound at 38% HBM peak.)

#define NUM_CODES 2048
#define CODE_DIM  256
#define BLOCK     256
#define WAVES_PER_BLOCK 4
#define VECS 8   // float4 vecs per lane: (2048/4) / 64 lanes = 8

__global__ __launch_bounds__(BLOCK) void gumbel_codebook_kernel(
    const float* __restrict__ logits,
    const float* __restrict__ gumbel,
    const float* __restrict__ codebook,
    float* __restrict__ z_out,   // [tokens, CODE_DIM]
    float* __restrict__ y_out)   // [tokens, NUM_CODES]
{
    const int lane  = threadIdx.x & 63;
    const int token = blockIdx.x * WAVES_PER_BLOCK + (threadIdx.x >> 6);

    const size_t row_off = (size_t)token * NUM_CODES;
    const float4* lrow = (const float4*)(logits + row_off);
    const float4* grow = (const float4*)(gumbel + row_off);

    // --- per-lane argmax over 32 codes; vec index increases with i, so
    // strict '>' keeps the first occurrence (jnp.argmax tie-break) ---
    float best = -INFINITY;
    int bestIdx = NUM_CODES;  // sentinel
#pragma unroll
    for (int i = 0; i < VECS; ++i) {
        const int vec  = lane + 64 * i;
        const int base = vec * 4;
        float4 l = lrow[vec];
        float4 g = grow[vec];
        float s0 = l.x + g.x;
        float s1 = l.y + g.y;
        float s2 = l.z + g.z;
        float s3 = l.w + g.w;
        if (s0 > best) { best = s0; bestIdx = base + 0; }
        if (s1 > best) { best = s1; bestIdx = base + 1; }
        if (s2 > best) { best = s2; bestIdx = base + 2; }
        if (s3 > best) { best = s3; bestIdx = base + 3; }
    }

    // --- 64-lane butterfly argmax; lower index wins ties ---
#pragma unroll
    for (int m = 32; m >= 1; m >>= 1) {
        float ob = __shfl_xor(best, m, 64);
        int   oi = __shfl_xor(bestIdx, m, 64);
        if (ob > best || (ob == best && oi < bestIdx)) { best = ob; bestIdx = oi; }
    }
    const int amax    = bestIdx;   // identical in all 64 lanes
    const int amaxVec = amax >> 2;

    // --- write y (one-hot), 8 coalesced float4 stores per lane ---
    float4* yrow = (float4*)(y_out + row_off);
#pragma unroll
    for (int i = 0; i < VECS; ++i) {
        const int vec = lane + 64 * i;
        float4 o = make_float4(0.f, 0.f, 0.f, 0.f);
        if (vec == amaxVec) ((float*)&o)[amax & 3] = 1.0f;
        yrow[vec] = o;
    }

    // --- write z = codebook[amax]: 64 lanes x float4 == 256 floats ---
    const float4* crow = (const float4*)(codebook + (size_t)amax * CODE_DIM);
    float4* zrow = (float4*)(z_out + (size_t)token * CODE_DIM);
    zrow[lane] = crow[lane];
}

extern "C" void kernel_launch(void* const* d_in, const int* in_sizes, int n_in,
                              void* d_out, int out_size, void* d_ws, size_t ws_size,
                              hipStream_t stream) {
    const float* logits   = (const float*)d_in[0];
    const float* gumbel   = (const float*)d_in[1];
    const float* codebook = (const float*)d_in[2];

    const int tokens = in_sizes[0] / NUM_CODES;  // 8*4096 = 32768

    float* z_out = (float*)d_out;                               // [tokens, 256]
    float* y_out = (float*)d_out + (size_t)tokens * CODE_DIM;   // [tokens, 2048]

    gumbel_codebook_kernel<<<tokens / WAVES_PER_BLOCK, BLOCK, 0, stream>>>(
        logits, gumbel, codebook, z_out, y_out);
}